// Round 2
// baseline (721.245 us; speedup 1.0000x reference)
//
#include <hip/hip_runtime.h>
#include <hip/hip_bf16.h>

typedef float f32x4 __attribute__((ext_vector_type(4)));
typedef __bf16 bf16x8 __attribute__((ext_vector_type(8)));
typedef __bf16 bf16x4 __attribute__((ext_vector_type(4)));

#define N_NODES 8192
#define IN_F    128
#define HID_F   256
#define OUT_F   64
#define ROWS_PB 8

// ---- Kernel 1: deg rowsum (+ optional fp32->bf16 convert of adj into adjb) ----
template <bool CVT>
__global__ __launch_bounds__(256) void k_degcvt(const float* __restrict__ adj,
                                                __bf16* __restrict__ adjb,
                                                float* __restrict__ d) {
  const int row = blockIdx.x;
  const int t = threadIdx.x;
  const f32x4* p = (const f32x4*)(adj + (size_t)row * N_NODES);
  bf16x4* q = (bf16x4*)(adjb + (size_t)row * N_NODES);
  float s = 0.f;
#pragma unroll
  for (int i = 0; i < N_NODES / (256 * 4); ++i) {  // 8 iters
    f32x4 v = p[i * 256 + t];
    s += v[0] + v[1] + v[2] + v[3];
    if (CVT) {
      bf16x4 o = {(__bf16)v[0], (__bf16)v[1], (__bf16)v[2], (__bf16)v[3]};
      q[i * 256 + t] = o;
    }
  }
#pragma unroll
  for (int off = 32; off > 0; off >>= 1) s += __shfl_down(s, off);
  __shared__ float red[4];
  if ((t & 63) == 0) red[t >> 6] = s;
  __syncthreads();
  if (t == 0) d[row] = rsqrtf(red[0] + red[1] + red[2] + red[3] + 1e-8f);
}

// ---------------- Kernel 2: Bt1[c][j] = bf16(d[j] * x[j][c]) ----------------
__global__ __launch_bounds__(256) void k_bt1(const float* __restrict__ x,
                                             const float* __restrict__ d,
                                             __bf16* __restrict__ Bt1) {
  __shared__ __bf16 tile[IN_F][64 + 2];
  const int t = threadIdx.x;
  const int j0 = blockIdx.x * 64;
#pragma unroll
  for (int rep = 0; rep < 32; ++rep) {
    int e = rep * 256 + t;
    int j = e >> 7, c = e & 127;
    tile[c][j] = (__bf16)(x[(size_t)(j0 + j) * IN_F + c] * d[j0 + j]);
  }
  __syncthreads();
#pragma unroll
  for (int rep = 0; rep < 32; ++rep) {
    int e = rep * 256 + t;
    int c = e >> 6, jj = e & 63;
    Bt1[(size_t)c * N_NODES + j0 + jj] = tile[c][jj];
  }
}

// A-fragment loaders: bf16 direct, or fp32 load + in-register convert
__device__ inline bf16x8 load_frag(const __bf16* p) { return *(const bf16x8*)p; }
__device__ inline bf16x8 load_frag(const float* p) {
  f32x4 a = *(const f32x4*)p;
  f32x4 b = *(const f32x4*)(p + 4);
  bf16x8 o = {(__bf16)a[0], (__bf16)a[1], (__bf16)a[2], (__bf16)a[3],
              (__bf16)b[0], (__bf16)b[1], (__bf16)b[2], (__bf16)b[3]};
  return o;
}

// ---- GEMM: out_rows = epi( adj[16 rows] @ Bt^T ), split-K across 4 waves ----
// EPI=0: out[m][c] = v * d[m]            (Y1, NC=128)
// EPI=1: out[m][c] = v * d[m] + bias[c]  (final, NC=64)
template <int NT, typename TA, int EPI>
__global__ __launch_bounds__(256) void k_gemm(const TA* __restrict__ adj,
                                              const __bf16* __restrict__ Bt,
                                              const float* __restrict__ dvec,
                                              const float* __restrict__ bias,
                                              float* __restrict__ out) {
  constexpr int KC = N_NODES / 4;  // 2048 per wave
  constexpr int NIT = KC / 32;     // 64
  constexpr int NC = NT * 16;
  const int lane = threadIdx.x & 63;
  const int w = threadIdx.x >> 6;  // wave = K-chunk
  const int m0 = blockIdx.x * 16;
  const int k0 = w * KC;
  const int r = lane & 15, q = lane >> 4;
  // A[m=lane&15][k=q*8+j] ; B[k=q*8+j][n=lane&15] from row-major B^T
  const TA* ap = adj + (size_t)(m0 + r) * N_NODES + k0 + q * 8;
  const __bf16* bp = Bt + (size_t)r * N_NODES + k0 + q * 8;

  f32x4 acc[NT];
#pragma unroll
  for (int ct = 0; ct < NT; ++ct) acc[ct] = (f32x4){0.f, 0.f, 0.f, 0.f};

  bf16x8 ab[2];
  bf16x8 bb[2][NT];
  ab[0] = load_frag(ap);
#pragma unroll
  for (int ct = 0; ct < NT; ++ct) bb[0][ct] = load_frag(bp + ct * 16 * N_NODES);

#pragma unroll 2
  for (int it = 0; it < NIT; ++it) {
    const int cur = it & 1, nxt = cur ^ 1;
    if (it + 1 < NIT) {
      const int off = (it + 1) * 32;
      ab[nxt] = load_frag(ap + off);
#pragma unroll
      for (int ct = 0; ct < NT; ++ct)
        bb[nxt][ct] = load_frag(bp + ct * 16 * N_NODES + off);
    }
#pragma unroll
    for (int ct = 0; ct < NT; ++ct)
      acc[ct] = __builtin_amdgcn_mfma_f32_16x16x32_bf16(ab[cur], bb[cur][ct],
                                                        acc[ct], 0, 0, 0);
  }

  // C/D layout: col = lane&15, row = q*4 + reg. Reduce 4 waves via LDS.
  __shared__ float red[4][16][NC + 1];
#pragma unroll
  for (int ct = 0; ct < NT; ++ct)
#pragma unroll
    for (int i = 0; i < 4; ++i) red[w][q * 4 + i][ct * 16 + r] = acc[ct][i];
  __syncthreads();
  for (int e = threadIdx.x; e < 16 * NC; e += 256) {
    const int row = e / NC, col = e % NC;
    float v = red[0][row][col] + red[1][row][col] + red[2][row][col] +
              red[3][row][col];
    const int gm = m0 + row;
    v *= dvec[gm];
    if (EPI == 1) v += bias[col];
    out[(size_t)gm * NC + col] = v;
  }
}

// ---- MLP per node row: h=relu(y@W1^T+b1); g=h@W2^T; Bt2[o][j]=bf16(d_j*g) ----
__global__ __launch_bounds__(256) void k_mlp(const float* __restrict__ Y1,
                                             const float* __restrict__ dvec,
                                             const float* __restrict__ W1,
                                             const float* __restrict__ b1,
                                             const float* __restrict__ W2,
                                             __bf16* __restrict__ Bt2) {
  __shared__ __align__(16) float yrow[IN_F];
  __shared__ __align__(16) float hrow[HID_F];
  __shared__ float gbuf[OUT_F][ROWS_PB];
  const int t = threadIdx.x;
  const int j0 = blockIdx.x * ROWS_PB;

  for (int rI = 0; rI < ROWS_PB; ++rI) {
    const int j = j0 + rI;
    if (t < IN_F) yrow[t] = Y1[(size_t)j * IN_F + t];
    __syncthreads();
    {
      float acc = b1[t];
      const f32x4* w1p = (const f32x4*)(W1 + (size_t)t * IN_F);
      const f32x4* yv = (const f32x4*)yrow;
#pragma unroll
      for (int c4 = 0; c4 < IN_F / 4; ++c4) {
        f32x4 wv = w1p[c4], yv4 = yv[c4];
        acc += wv[0] * yv4[0] + wv[1] * yv4[1] + wv[2] * yv4[2] + wv[3] * yv4[3];
      }
      hrow[t] = fmaxf(acc, 0.f);
    }
    __syncthreads();
    if (t < OUT_F) {
      float acc = 0.f;
      const f32x4* w2p = (const f32x4*)(W2 + (size_t)t * HID_F);
      const f32x4* hv = (const f32x4*)hrow;
#pragma unroll
      for (int h4 = 0; h4 < HID_F / 4; ++h4) {
        f32x4 wv = w2p[h4], hv4 = hv[h4];
        acc += wv[0] * hv4[0] + wv[1] * hv4[1] + wv[2] * hv4[2] + wv[3] * hv4[3];
      }
      gbuf[t][rI] = acc * dvec[j];
    }
    __syncthreads();
  }
  const int o = t >> 2;
  const int i0 = (t & 3) * 2;
  Bt2[(size_t)o * N_NODES + j0 + i0] = (__bf16)gbuf[o][i0];
  Bt2[(size_t)o * N_NODES + j0 + i0 + 1] = (__bf16)gbuf[o][i0 + 1];
}

extern "C" void kernel_launch(void* const* d_in, const int* in_sizes, int n_in,
                              void* d_out, int out_size, void* d_ws,
                              size_t ws_size, hipStream_t stream) {
  const float* x   = (const float*)d_in[0];
  const float* adj = (const float*)d_in[1];
  const float* W1  = (const float*)d_in[2];
  const float* b1  = (const float*)d_in[3];
  const float* W2  = (const float*)d_in[4];
  const float* b2  = (const float*)d_in[5];
  float* out = (float*)d_out;
  char* ws = (char*)d_ws;

  const size_t SZ_ADJB = (size_t)N_NODES * N_NODES * 2;        // 128 MiB
  const size_t SZ_D    = (size_t)N_NODES * 4;                  // 32 KiB
  const size_t SZ_BT1  = (size_t)IN_F * N_NODES * 2;           // 2 MiB
  const size_t SZ_Y1   = (size_t)N_NODES * IN_F * 4;           // 4 MiB
  const size_t need_small = SZ_D + SZ_BT1 + SZ_Y1 + (size_t)OUT_F * N_NODES * 2;
  const bool big = ws_size >= SZ_ADJB + need_small;

  size_t off = big ? SZ_ADJB : 0;
  __bf16* adjb = (__bf16*)ws;                 // only used when big
  float*  dvec = (float*)(ws + off);          off += SZ_D;
  __bf16* Bt1  = (__bf16*)(ws + off);         off += SZ_BT1;
  float*  Y1   = (float*)(ws + off);          off += SZ_Y1;
  __bf16* Bt2  = (__bf16*)(ws + off);

  if (big) {
    hipLaunchKernelGGL((k_degcvt<true>), dim3(N_NODES), dim3(256), 0, stream,
                       adj, adjb, dvec);
  } else {
    hipLaunchKernelGGL((k_degcvt<false>), dim3(N_NODES), dim3(256), 0, stream,
                       adj, adjb, dvec);
  }
  hipLaunchKernelGGL(k_bt1, dim3(N_NODES / 64), dim3(256), 0, stream, x, dvec, Bt1);
  if (big) {
    hipLaunchKernelGGL((k_gemm<8, __bf16, 0>), dim3(N_NODES / 16), dim3(256), 0,
                       stream, adjb, Bt1, dvec, (const float*)nullptr, Y1);
  } else {
    hipLaunchKernelGGL((k_gemm<8, float, 0>), dim3(N_NODES / 16), dim3(256), 0,
                       stream, adj, Bt1, dvec, (const float*)nullptr, Y1);
  }
  hipLaunchKernelGGL(k_mlp, dim3(N_NODES / ROWS_PB), dim3(256), 0, stream, Y1,
                     dvec, W1, b1, W2, Bt2);
  if (big) {
    hipLaunchKernelGGL((k_gemm<4, __bf16, 1>), dim3(N_NODES / 16), dim3(256), 0,
                       stream, adjb, Bt2, dvec, b2, out);
  } else {
    hipLaunchKernelGGL((k_gemm<4, float, 1>), dim3(N_NODES / 16), dim3(256), 0,
                       stream, adj, Bt2, dvec, b2, out);
  }
}

// Round 3
// 608.192 us; speedup vs baseline: 1.1859x; 1.1859x over previous
//
#include <hip/hip_runtime.h>
#include <hip/hip_bf16.h>

typedef float f32x4 __attribute__((ext_vector_type(4)));
typedef __bf16 bf16x8 __attribute__((ext_vector_type(8)));
typedef __bf16 bf16x4 __attribute__((ext_vector_type(4)));

#define N_NODES 8192
#define IN_F    128
#define HID_F   256
#define OUT_F   64

// ---- Kernel 1: deg rowsum (+ optional fp32->bf16 convert of adj into adjb) ----
template <bool CVT>
__global__ __launch_bounds__(256) void k_degcvt(const float* __restrict__ adj,
                                                __bf16* __restrict__ adjb,
                                                float* __restrict__ d) {
  const int row = blockIdx.x;
  const int t = threadIdx.x;
  const f32x4* p = (const f32x4*)(adj + (size_t)row * N_NODES);
  bf16x4* q = (bf16x4*)(adjb + (size_t)row * N_NODES);
  float s = 0.f;
#pragma unroll
  for (int i = 0; i < N_NODES / (256 * 4); ++i) {  // 8 iters
    f32x4 v = p[i * 256 + t];
    s += v[0] + v[1] + v[2] + v[3];
    if (CVT) {
      bf16x4 o = {(__bf16)v[0], (__bf16)v[1], (__bf16)v[2], (__bf16)v[3]};
      q[i * 256 + t] = o;
    }
  }
#pragma unroll
  for (int off = 32; off > 0; off >>= 1) s += __shfl_down(s, off);
  __shared__ float red[4];
  if ((t & 63) == 0) red[t >> 6] = s;
  __syncthreads();
  if (t == 0) d[row] = rsqrtf(red[0] + red[1] + red[2] + red[3] + 1e-8f);
}

// ---------------- Kernel 2: Bt1[c][j] = bf16(d[j] * x[j][c]) ----------------
__global__ __launch_bounds__(256) void k_bt1(const float* __restrict__ x,
                                             const float* __restrict__ d,
                                             __bf16* __restrict__ Bt1) {
  __shared__ __bf16 tile[IN_F][64 + 2];
  const int t = threadIdx.x;
  const int j0 = blockIdx.x * 64;
#pragma unroll
  for (int rep = 0; rep < 32; ++rep) {
    int e = rep * 256 + t;
    int j = e >> 7, c = e & 127;
    tile[c][j] = (__bf16)(x[(size_t)(j0 + j) * IN_F + c] * d[j0 + j]);
  }
  __syncthreads();
#pragma unroll
  for (int rep = 0; rep < 32; ++rep) {
    int e = rep * 256 + t;
    int c = e >> 6, jj = e & 63;
    Bt1[(size_t)c * N_NODES + j0 + jj] = tile[c][jj];
  }
}

// fragment loaders: bf16 direct, or fp32 load + in-register convert
__device__ inline bf16x8 load_frag(const __bf16* p) { return *(const bf16x8*)p; }
__device__ inline bf16x8 load_frag(const float* p) {
  f32x4 a = *(const f32x4*)p;
  f32x4 b = *(const f32x4*)(p + 4);
  bf16x8 o = {(__bf16)a[0], (__bf16)a[1], (__bf16)a[2], (__bf16)a[3],
              (__bf16)b[0], (__bf16)b[1], (__bf16)b[2], (__bf16)b[3]};
  return o;
}

// ---- GEMM partials: P[s][m][c] = adj[m, s-chunk] @ Bt^T  (raw fp32 sums) ----
// grid = (row_groups, 4 splits); block = 4 waves, wave w covers K-sub 512.
template <int TM, int NT, typename TA>
__global__ __launch_bounds__(256, 4) void k_gemm_p(const TA* __restrict__ adj,
                                                   const __bf16* __restrict__ Bt,
                                                   float* __restrict__ P) {
  constexpr int NC = NT * 16;
  constexpr int MR = TM * 16;
  constexpr int NIT = 16;  // 512 / 32
  const int lane = threadIdx.x & 63;
  const int w = threadIdx.x >> 6;
  const int s = blockIdx.y;
  const int m0 = blockIdx.x * MR;
  const int k0 = s * 2048 + w * 512;
  const int r = lane & 15, q = lane >> 4;
  // A[m=lane&15][k=q*8+j] ; B[k=q*8+j][n=lane&15] from row-major B^T
  const TA* ap[TM];
#pragma unroll
  for (int tm = 0; tm < TM; ++tm)
    ap[tm] = adj + (size_t)(m0 + tm * 16 + r) * N_NODES + k0 + q * 8;
  const __bf16* bp = Bt + (size_t)r * N_NODES + k0 + q * 8;

  f32x4 acc[TM][NT];
#pragma unroll
  for (int tm = 0; tm < TM; ++tm)
#pragma unroll
    for (int ct = 0; ct < NT; ++ct) acc[tm][ct] = (f32x4){0.f, 0.f, 0.f, 0.f};

  bf16x8 ab[2][TM];
  bf16x8 bb[2][NT];
#pragma unroll
  for (int tm = 0; tm < TM; ++tm) ab[0][tm] = load_frag(ap[tm]);
#pragma unroll
  for (int ct = 0; ct < NT; ++ct) bb[0][ct] = load_frag(bp + ct * 16 * N_NODES);

#pragma unroll 2
  for (int it = 0; it < NIT; ++it) {
    const int cur = it & 1, nxt = cur ^ 1;
    if (it + 1 < NIT) {  // register double-buffer: next iter's loads in flight
      const int off = (it + 1) * 32;
#pragma unroll
      for (int tm = 0; tm < TM; ++tm) ab[nxt][tm] = load_frag(ap[tm] + off);
#pragma unroll
      for (int ct = 0; ct < NT; ++ct)
        bb[nxt][ct] = load_frag(bp + ct * 16 * N_NODES + off);
    }
#pragma unroll
    for (int tm = 0; tm < TM; ++tm)
#pragma unroll
      for (int ct = 0; ct < NT; ++ct)
        acc[tm][ct] = __builtin_amdgcn_mfma_f32_16x16x32_bf16(
            ab[cur][tm], bb[cur][ct], acc[tm][ct], 0, 0, 0);
  }

  // C/D layout: col = lane&15, row = q*4 + reg. Reduce 4 waves via LDS.
  __shared__ float red[4][MR][NC + 1];
#pragma unroll
  for (int tm = 0; tm < TM; ++tm)
#pragma unroll
    for (int ct = 0; ct < NT; ++ct)
#pragma unroll
      for (int i = 0; i < 4; ++i)
        red[w][tm * 16 + q * 4 + i][ct * 16 + r] = acc[tm][ct][i];
  __syncthreads();
  for (int e = threadIdx.x; e < MR * NC; e += 256) {
    const int row = e / NC, col = e % NC;
    float v = red[0][row][col] + red[1][row][col] + red[2][row][col] +
              red[3][row][col];
    P[((size_t)s * N_NODES + m0 + row) * NC + col] = v;
  }
}

// ---- reduce P1 + MLP (bf16 MFMA) + build Bt2, 16 nodes per block ----
// y = d*sum_s(P1); h = relu(y@W1^T + b1); g = h@W2^T; Bt2[o][j] = bf16(d_j*g)
__global__ __launch_bounds__(256) void k_red_mlp(const float* __restrict__ P1,
                                                 const float* __restrict__ dvec,
                                                 const float* __restrict__ W1,
                                                 const float* __restrict__ b1,
                                                 const float* __restrict__ W2,
                                                 __bf16* __restrict__ Bt2) {
  __shared__ __align__(16) float y[16][IN_F + 4];      // +4 pad: A-frag reads
  __shared__ __align__(16) __bf16 h[16][HID_F + 8];    // +8 pad
  __shared__ __align__(16) float gl[OUT_F][20];
  __shared__ float dl[16];
  const int t = threadIdx.x;
  const int lane = t & 63;
  const int w = t >> 6;
  const int r = lane & 15, q = lane >> 4;
  const int j0 = blockIdx.x * 16;

  if (t < 16) dl[t] = dvec[j0 + t];
  for (int e = t; e < 16 * IN_F; e += 256) {
    const int jj = e >> 7, c = e & 127;
    const size_t base = (size_t)(j0 + jj) * IN_F + c;
    const size_t pl = (size_t)N_NODES * IN_F;
    float v = P1[base] + P1[base + pl] + P1[base + 2 * pl] + P1[base + 3 * pl];
    y[jj][c] = v * dvec[j0 + jj];
  }
  __syncthreads();

  // stage 2: h tile. wave w -> hid cols [w*64, w*64+64)
  f32x4 hacc[4];
#pragma unroll
  for (int tt = 0; tt < 4; ++tt) hacc[tt] = (f32x4){0.f, 0.f, 0.f, 0.f};
#pragma unroll
  for (int kt = 0; kt < 4; ++kt) {
    bf16x8 afr = load_frag((const float*)&y[r][kt * 32 + q * 8]);
#pragma unroll
    for (int tt = 0; tt < 4; ++tt) {
      const int col = w * 64 + tt * 16 + r;
      bf16x8 bfr = load_frag(W1 + (size_t)col * IN_F + kt * 32 + q * 8);
      hacc[tt] = __builtin_amdgcn_mfma_f32_16x16x32_bf16(afr, bfr, hacc[tt], 0, 0, 0);
    }
  }
#pragma unroll
  for (int tt = 0; tt < 4; ++tt) {
    const int col = w * 64 + tt * 16 + r;
    const float bias = b1[col];
#pragma unroll
    for (int i = 0; i < 4; ++i)
      h[q * 4 + i][col] = (__bf16)fmaxf(hacc[tt][i] + bias, 0.f);
  }
  __syncthreads();

  // stage 3: g tile. wave w -> out cols [w*16, w*16+16), K=256
  f32x4 gacc = (f32x4){0.f, 0.f, 0.f, 0.f};
  const int o = w * 16 + r;
#pragma unroll
  for (int kt = 0; kt < 8; ++kt) {
    bf16x8 afr = *(const bf16x8*)&h[r][kt * 32 + q * 8];
    bf16x8 bfr = load_frag(W2 + (size_t)o * HID_F + kt * 32 + q * 8);
    gacc = __builtin_amdgcn_mfma_f32_16x16x32_bf16(afr, bfr, gacc, 0, 0, 0);
  }
#pragma unroll
  for (int i = 0; i < 4; ++i) gl[o][q * 4 + i] = gacc[i];
  __syncthreads();

  const int oo = t >> 2, r0 = (t & 3) * 4;
  bf16x4 ov;
#pragma unroll
  for (int rr = 0; rr < 4; ++rr)
    ov[rr] = (__bf16)(gl[oo][r0 + rr] * dl[r0 + rr]);
  *(bf16x4*)(Bt2 + (size_t)oo * N_NODES + j0 + r0) = ov;
}

// ---- k_out: out[j][o] = d[j]*sum_s P2 + b2[o] ----
__global__ __launch_bounds__(256) void k_out(const float* __restrict__ P2,
                                             const float* __restrict__ dvec,
                                             const float* __restrict__ b2,
                                             float* __restrict__ out) {
  const int idx = blockIdx.x * 256 + threadIdx.x;
  const int j = idx >> 6, o = idx & 63;
  const size_t pl = (size_t)N_NODES * OUT_F;
  float s = P2[idx] + P2[idx + pl] + P2[idx + 2 * pl] + P2[idx + 3 * pl];
  out[idx] = s * dvec[j] + b2[o];
}

extern "C" void kernel_launch(void* const* d_in, const int* in_sizes, int n_in,
                              void* d_out, int out_size, void* d_ws,
                              size_t ws_size, hipStream_t stream) {
  const float* x   = (const float*)d_in[0];
  const float* adj = (const float*)d_in[1];
  const float* W1  = (const float*)d_in[2];
  const float* b1  = (const float*)d_in[3];
  const float* W2  = (const float*)d_in[4];
  const float* b2  = (const float*)d_in[5];
  float* out = (float*)d_out;
  char* ws = (char*)d_ws;

  const size_t SZ_ADJB = (size_t)N_NODES * N_NODES * 2;       // 128 MiB
  const size_t SZ_D    = (size_t)N_NODES * 4;                 // 32 KiB
  const size_t SZ_BT1  = (size_t)IN_F * N_NODES * 2;          // 2 MiB
  const size_t SZ_P1   = (size_t)4 * N_NODES * IN_F * 4;      // 16 MiB
  const size_t SZ_BT2  = (size_t)OUT_F * N_NODES * 2;         // 1 MiB
  const size_t SZ_P2   = (size_t)4 * N_NODES * OUT_F * 4;     // 8 MiB
  const size_t need_small = SZ_D + SZ_BT1 + SZ_P1 + SZ_BT2 + SZ_P2;
  const bool big = ws_size >= SZ_ADJB + need_small;

  size_t off = big ? SZ_ADJB : 0;
  __bf16* adjb = (__bf16*)ws;  // only used when big
  float*  dvec = (float*)(ws + off);   off += SZ_D;
  __bf16* Bt1  = (__bf16*)(ws + off);  off += SZ_BT1;
  float*  P1   = (float*)(ws + off);   off += SZ_P1;
  __bf16* Bt2  = (__bf16*)(ws + off);  off += SZ_BT2;
  float*  P2   = (float*)(ws + off);

  if (big) {
    hipLaunchKernelGGL((k_degcvt<true>), dim3(N_NODES), dim3(256), 0, stream,
                       adj, adjb, dvec);
  } else {
    hipLaunchKernelGGL((k_degcvt<false>), dim3(N_NODES), dim3(256), 0, stream,
                       adj, adjb, dvec);
  }
  hipLaunchKernelGGL(k_bt1, dim3(N_NODES / 64), dim3(256), 0, stream, x, dvec, Bt1);
  if (big) {
    hipLaunchKernelGGL((k_gemm_p<1, 8, __bf16>), dim3(N_NODES / 16, 4),
                       dim3(256), 0, stream, adjb, Bt1, P1);
  } else {
    hipLaunchKernelGGL((k_gemm_p<1, 8, float>), dim3(N_NODES / 16, 4),
                       dim3(256), 0, stream, adj, Bt1, P1);
  }
  hipLaunchKernelGGL(k_red_mlp, dim3(N_NODES / 16), dim3(256), 0, stream, P1,
                     dvec, W1, b1, W2, Bt2);
  if (big) {
    hipLaunchKernelGGL((k_gemm_p<2, 4, __bf16>), dim3(N_NODES / 32, 4),
                       dim3(256), 0, stream, adjb, Bt2, P2);
  } else {
    hipLaunchKernelGGL((k_gemm_p<2, 4, float>), dim3(N_NODES / 32, 4),
                       dim3(256), 0, stream, adj, Bt2, P2);
  }
  hipLaunchKernelGGL(k_out, dim3((N_NODES * OUT_F) / 256), dim3(256), 0, stream,
                     P2, dvec, b2, out);
}

// Round 4
// 486.752 us; speedup vs baseline: 1.4818x; 1.2495x over previous
//
#include <hip/hip_runtime.h>
#include <hip/hip_bf16.h>

typedef float f32x4 __attribute__((ext_vector_type(4)));
typedef __bf16 bf16x8 __attribute__((ext_vector_type(8)));
typedef __bf16 bf16x4 __attribute__((ext_vector_type(4)));

#define N_NODES 8192
#define IN_F    128
#define HID_F   256
#define OUT_F   64
#define SPLIT1  8
#define SPLIT2  16

// async global->LDS DMA, 16B per lane. LDS dst = wave-uniform base + lane*16.
// Generic LDS pointer's low 32 bits are the LDS byte offset on amdgcn.
__device__ __forceinline__ void dma16(const void* g, void* l) {
  __builtin_amdgcn_global_load_lds(
      (const __attribute__((address_space(1))) void*)g,
      (__attribute__((address_space(3))) void*)(uint32_t)(uintptr_t)l, 16, 0, 0);
}

// ---- Kernel 1: deg rowsum + fp32->bf16 convert of adj into adjb ----
__global__ __launch_bounds__(256) void k_degcvt(const float* __restrict__ adj,
                                                __bf16* __restrict__ adjb,
                                                float* __restrict__ d) {
  const int row = blockIdx.x;
  const int t = threadIdx.x;
  const f32x4* p = (const f32x4*)(adj + (size_t)row * N_NODES);
  bf16x4* q = (bf16x4*)(adjb + (size_t)row * N_NODES);
  float s = 0.f;
#pragma unroll
  for (int i = 0; i < N_NODES / (256 * 4); ++i) {
    f32x4 v = p[i * 256 + t];
    s += v[0] + v[1] + v[2] + v[3];
    bf16x4 o = {(__bf16)v[0], (__bf16)v[1], (__bf16)v[2], (__bf16)v[3]};
    q[i * 256 + t] = o;
  }
#pragma unroll
  for (int off = 32; off > 0; off >>= 1) s += __shfl_down(s, off);
  __shared__ float red[4];
  if ((t & 63) == 0) red[t >> 6] = s;
  __syncthreads();
  if (t == 0) d[row] = rsqrtf(red[0] + red[1] + red[2] + red[3] + 1e-8f);
}

// ---- Kernel 2: Bt1[c][j] = bf16(d[j] * x[j][c]) ----
__global__ __launch_bounds__(256) void k_bt1(const float* __restrict__ x,
                                             const float* __restrict__ d,
                                             __bf16* __restrict__ Bt1) {
  __shared__ __bf16 tile[IN_F][64 + 2];
  const int t = threadIdx.x;
  const int j0 = blockIdx.x * 64;
#pragma unroll
  for (int rep = 0; rep < 32; ++rep) {
    int e = rep * 256 + t;
    int j = e >> 7, c = e & 127;
    tile[c][j] = (__bf16)(x[(size_t)(j0 + j) * IN_F + c] * d[j0 + j]);
  }
  __syncthreads();
#pragma unroll
  for (int rep = 0; rep < 32; ++rep) {
    int e = rep * 256 + t;
    int c = e >> 6, jj = e & 63;
    Bt1[(size_t)c * N_NODES + j0 + jj] = tile[c][jj];
  }
}

__device__ inline bf16x8 load_frag(const float* p) {
  f32x4 a = *(const f32x4*)p;
  f32x4 b = *(const f32x4*)(p + 4);
  bf16x8 o = {(__bf16)a[0], (__bf16)a[1], (__bf16)a[2], (__bf16)a[3],
              (__bf16)b[0], (__bf16)b[1], (__bf16)b[2], (__bf16)b[3]};
  return o;
}

// ---- DMA-staged MFMA GEMM partials: P[s][m][c] = adj_tile @ Bt^T ----
// Block tile: BM x BN (BM=WGM*64, BN=WGN*64), 4 waves in WGM x WGN grid,
// wave tile 64x64 (TM=4,NT=4). K-chunk KC per blockIdx.y. LDS double-buffered,
// staged via global_load_lds w/ chunk swizzle c ^= (row>>1)&3 (bank-friendly).
template <int WGM, int WGN, int KC>
__global__ __launch_bounds__(256, 2) void k_gemm_dma(
    const __bf16* __restrict__ A, const __bf16* __restrict__ Bt,
    float* __restrict__ P) {
  constexpr int BM = WGM * 64, BN = WGN * 64;
  constexpr int ANI = BM / 64, BNI = BN / 64;   // staging instrs per thread
  constexpr int ABYTES = BM * 64;               // A region bytes per stage
  constexpr int STAGE = (BM + BN) * 64;         // one stage buffer
  constexpr int NIT = KC / 32;

  __shared__ __align__(16) char sm[2 * STAGE];

  const int t = threadIdx.x;
  const int w = t >> 6, lane = t & 63;
  const int r = lane & 15, q = lane >> 4;
  const int wm = (WGN == 1) ? w : (w >> 1);
  const int wn = (WGN == 1) ? 0 : (w & 1);
  const int m0 = blockIdx.x * BM;
  const int ks = blockIdx.y;
  const int k0 = ks * KC;

  // staging source pointers (per-thread): chunk L = kk*256 + t -> row n=L>>2,
  // chunk slot c=L&3, stored swizzled: holds global chunk c ^ ((n>>1)&3).
  const int n_ = t >> 2;
  const int csw = (t & 3) ^ ((t >> 3) & 3);
  const __bf16* a_src[ANI];
  const __bf16* b_src[BNI];
#pragma unroll
  for (int kk = 0; kk < ANI; ++kk)
    a_src[kk] = A + (size_t)(m0 + n_ + 64 * kk) * N_NODES + k0 + csw * 8;
#pragma unroll
  for (int kk = 0; kk < BNI; ++kk)
    b_src[kk] = Bt + (size_t)(n_ + 64 * kk) * N_NODES + k0 + csw * 8;

  // fragment LDS byte offsets (loop-invariant): row*64 + (q^((row>>1)&3))*16
  int offA[4], offB[4];
#pragma unroll
  for (int tm = 0; tm < 4; ++tm) {
    const int row = wm * 64 + tm * 16 + r;
    offA[tm] = row * 64 + ((q ^ ((row >> 1) & 3)) << 4);
  }
#pragma unroll
  for (int ct = 0; ct < 4; ++ct) {
    const int row = wn * 64 + ct * 16 + r;
    offB[ct] = ABYTES + row * 64 + ((q ^ ((row >> 1) & 3)) << 4);
  }

  f32x4 acc[4][4];
#pragma unroll
  for (int tm = 0; tm < 4; ++tm)
#pragma unroll
    for (int ct = 0; ct < 4; ++ct) acc[tm][ct] = (f32x4){0.f, 0.f, 0.f, 0.f};

  // prologue stage into buf 0
  {
    char* sb = sm;
#pragma unroll
    for (int kk = 0; kk < ANI; ++kk) {
      dma16(a_src[kk], sb + kk * 4096 + (w << 10));
      a_src[kk] += 32;
    }
#pragma unroll
    for (int kk = 0; kk < BNI; ++kk) {
      dma16(b_src[kk], sb + ABYTES + kk * 4096 + (w << 10));
      b_src[kk] += 32;
    }
  }
  __syncthreads();

#pragma unroll 2
  for (int it = 0; it < NIT; ++it) {
    char* cb = sm + (it & 1) * STAGE;
    if (it + 1 < NIT) {  // async-stage next K-chunk into other buffer
      char* nb = sm + ((it + 1) & 1) * STAGE;
#pragma unroll
      for (int kk = 0; kk < ANI; ++kk) {
        dma16(a_src[kk], nb + kk * 4096 + (w << 10));
        a_src[kk] += 32;
      }
#pragma unroll
      for (int kk = 0; kk < BNI; ++kk) {
        dma16(b_src[kk], nb + ABYTES + kk * 4096 + (w << 10));
        b_src[kk] += 32;
      }
    }
    bf16x8 af[4], bfr[4];
#pragma unroll
    for (int tm = 0; tm < 4; ++tm) af[tm] = *(const bf16x8*)(cb + offA[tm]);
#pragma unroll
    for (int ct = 0; ct < 4; ++ct) bfr[ct] = *(const bf16x8*)(cb + offB[ct]);
#pragma unroll
    for (int tm = 0; tm < 4; ++tm)
#pragma unroll
      for (int ct = 0; ct < 4; ++ct)
        acc[tm][ct] = __builtin_amdgcn_mfma_f32_16x16x32_bf16(
            af[tm], bfr[ct], acc[tm][ct], 0, 0, 0);
    __syncthreads();  // drains staging (vmcnt) + guards buffer reuse
  }

  // epilogue: C/D layout col=lane&15, row=q*4+reg
  float* pout =
      P + ((size_t)ks * N_NODES + m0 + wm * 64 + q * 4) * BN + wn * 64 + r;
#pragma unroll
  for (int tm = 0; tm < 4; ++tm)
#pragma unroll
    for (int ct = 0; ct < 4; ++ct)
#pragma unroll
      for (int i = 0; i < 4; ++i)
        pout[(size_t)(tm * 16 + i) * BN + ct * 16] = acc[tm][ct][i];
}

// ---- reduce P1 + MLP (bf16 MFMA) + build Bt2, 16 nodes per block ----
__global__ __launch_bounds__(256) void k_red_mlp(const float* __restrict__ P1,
                                                 const float* __restrict__ dvec,
                                                 const float* __restrict__ W1,
                                                 const float* __restrict__ b1,
                                                 const float* __restrict__ W2,
                                                 __bf16* __restrict__ Bt2) {
  __shared__ __align__(16) float y[16][IN_F + 4];
  __shared__ __align__(16) __bf16 h[16][HID_F + 8];
  __shared__ __align__(16) float gl[OUT_F][20];
  __shared__ float dl[16];
  const int t = threadIdx.x;
  const int lane = t & 63;
  const int w = t >> 6;
  const int r = lane & 15, q = lane >> 4;
  const int j0 = blockIdx.x * 16;

  if (t < 16) dl[t] = dvec[j0 + t];
  const size_t plane4 = (size_t)N_NODES * IN_F / 4;
  for (int e = t; e < 16 * IN_F / 4; e += 256) {
    const int jj = e >> 5, c4 = e & 31;
    const size_t base = (size_t)(j0 + jj) * (IN_F / 4) + c4;
    f32x4 v = (f32x4){0.f, 0.f, 0.f, 0.f};
#pragma unroll
    for (int s = 0; s < SPLIT1; ++s) v += ((const f32x4*)P1)[base + s * plane4];
    const float dj = dvec[j0 + jj];
    v *= dj;
    *(f32x4*)&y[jj][c4 * 4] = v;
  }
  __syncthreads();

  // h tile: wave w -> hid cols [w*64, w*64+64)
  f32x4 hacc[4];
#pragma unroll
  for (int tt = 0; tt < 4; ++tt) hacc[tt] = (f32x4){0.f, 0.f, 0.f, 0.f};
#pragma unroll
  for (int kt = 0; kt < 4; ++kt) {
    bf16x8 afr = load_frag((const float*)&y[r][kt * 32 + q * 8]);
#pragma unroll
    for (int tt = 0; tt < 4; ++tt) {
      const int col = w * 64 + tt * 16 + r;
      bf16x8 bfr = load_frag(W1 + (size_t)col * IN_F + kt * 32 + q * 8);
      hacc[tt] = __builtin_amdgcn_mfma_f32_16x16x32_bf16(afr, bfr, hacc[tt], 0, 0, 0);
    }
  }
#pragma unroll
  for (int tt = 0; tt < 4; ++tt) {
    const int col = w * 64 + tt * 16 + r;
    const float bias = b1[col];
#pragma unroll
    for (int i = 0; i < 4; ++i)
      h[q * 4 + i][col] = (__bf16)fmaxf(hacc[tt][i] + bias, 0.f);
  }
  __syncthreads();

  // g tile: wave w -> out cols [w*16, w*16+16), K=256
  f32x4 gacc = (f32x4){0.f, 0.f, 0.f, 0.f};
  const int o = w * 16 + r;
#pragma unroll
  for (int kt = 0; kt < 8; ++kt) {
    bf16x8 afr = *(const bf16x8*)&h[r][kt * 32 + q * 8];
    bf16x8 bfr = load_frag(W2 + (size_t)o * HID_F + kt * 32 + q * 8);
    gacc = __builtin_amdgcn_mfma_f32_16x16x32_bf16(afr, bfr, gacc, 0, 0, 0);
  }
#pragma unroll
  for (int i = 0; i < 4; ++i) gl[o][q * 4 + i] = gacc[i];
  __syncthreads();

  const int oo = t >> 2, r0 = (t & 3) * 4;
  bf16x4 ov;
#pragma unroll
  for (int rr = 0; rr < 4; ++rr) ov[rr] = (__bf16)(gl[oo][r0 + rr] * dl[r0 + rr]);
  *(bf16x4*)(Bt2 + (size_t)oo * N_NODES + j0 + r0) = ov;
}

// ---- k_out: out[j][o] = d[j]*sum_s P2 + b2[o] (vectorized f32x4) ----
__global__ __launch_bounds__(256) void k_out(const float* __restrict__ P2,
                                             const float* __restrict__ dvec,
                                             const float* __restrict__ b2,
                                             float* __restrict__ out) {
  const int idx = blockIdx.x * 256 + threadIdx.x;  // over N*OUT/4 vec4
  const int j = idx >> 4, o4 = idx & 15;
  const size_t plane4 = (size_t)N_NODES * OUT_F / 4;
  f32x4 s = (f32x4){0.f, 0.f, 0.f, 0.f};
#pragma unroll
  for (int sp = 0; sp < SPLIT2; ++sp) s += ((const f32x4*)P2)[idx + sp * plane4];
  s *= dvec[j];
  s += ((const f32x4*)b2)[o4];
  ((f32x4*)out)[idx] = s;
}

extern "C" void kernel_launch(void* const* d_in, const int* in_sizes, int n_in,
                              void* d_out, int out_size, void* d_ws,
                              size_t ws_size, hipStream_t stream) {
  const float* x   = (const float*)d_in[0];
  const float* adj = (const float*)d_in[1];
  const float* W1  = (const float*)d_in[2];
  const float* b1  = (const float*)d_in[3];
  const float* W2  = (const float*)d_in[4];
  const float* b2  = (const float*)d_in[5];
  float* out = (float*)d_out;
  char* ws = (char*)d_ws;

  size_t off = 0;
  __bf16* adjb = (__bf16*)(ws + off); off += (size_t)N_NODES * N_NODES * 2;  // 128Mi
  float*  dvec = (float*)(ws + off);  off += (size_t)N_NODES * 4;
  __bf16* Bt1  = (__bf16*)(ws + off); off += (size_t)IN_F * N_NODES * 2;
  float*  P1   = (float*)(ws + off);  off += (size_t)SPLIT1 * N_NODES * IN_F * 4;
  __bf16* Bt2  = (__bf16*)(ws + off); off += (size_t)OUT_F * N_NODES * 2;
  float*  P2   = (float*)(ws + off);  // +32Mi, total ~195 MiB

  hipLaunchKernelGGL(k_degcvt, dim3(N_NODES), dim3(256), 0, stream, adj, adjb, dvec);
  hipLaunchKernelGGL(k_bt1, dim3(N_NODES / 64), dim3(256), 0, stream, x, dvec, Bt1);
  // GEMM1: block 128x128, split-K=8 -> grid (64,8)
  hipLaunchKernelGGL((k_gemm_dma<2, 2, N_NODES / SPLIT1>),
                     dim3(N_NODES / 128, SPLIT1), dim3(256), 0, stream,
                     adjb, Bt1, P1);
  hipLaunchKernelGGL(k_red_mlp, dim3(N_NODES / 16), dim3(256), 0, stream, P1,
                     dvec, W1, b1, W2, Bt2);
  // GEMM2: block 256x64, split-K=16 -> grid (32,16)
  hipLaunchKernelGGL((k_gemm_dma<4, 1, N_NODES / SPLIT2>),
                     dim3(N_NODES / 256, SPLIT2), dim3(256), 0, stream,
                     adjb, Bt2, P2);
  hipLaunchKernelGGL(k_out, dim3((N_NODES * OUT_F / 4) / 256), dim3(256), 0,
                     stream, P2, dvec, b2, out);
}